// Round 7
// baseline (501.948 us; speedup 1.0000x reference)
//
#include <hip/hip_runtime.h>
#include <math.h>

#define DM   1024
#define NH   16
#define DH   64
#define SEQ  2048
#define BATCH 4

typedef __attribute__((ext_vector_type(8)))  short short8;
typedef __attribute__((ext_vector_type(4)))  float f32x4;
typedef __attribute__((ext_vector_type(16))) float f32x16;

// ---- fp32 -> bf16 hi/lo split helpers (RNE) -------------------------------
static __device__ __forceinline__ unsigned short f2bf(float f) {
    unsigned u = __float_as_uint(f);
    unsigned r = (u + 0x7fffu + ((u >> 16) & 1u)) >> 16;
    return (unsigned short)r;
}
static __device__ __forceinline__ float bf2f(unsigned short h) {
    return __uint_as_float(((unsigned)h) << 16);
}

// swizzled byte offset inside a [rows][128B] LDS tile (T2-style, G4 rule)
static __device__ __forceinline__ int swz(int row, int cbyte) {
    return row * 128 + (cbyte ^ ((row & 7) << 4));
}

#define GLD(gp, lp) __builtin_amdgcn_global_load_lds( \
    (const __attribute__((address_space(1))) void*)(gp), \
    (__attribute__((address_space(3))) void*)(lp), 16, 0, 0)

// ---- prep: elementwise split fp32 -> (hi, lo) bf16, same layout -----------
__global__ __launch_bounds__(256) void split_hl(
    const float* __restrict__ in, unsigned short* __restrict__ hi,
    unsigned short* __restrict__ lo, int n4)
{
    int i = blockIdx.x * 256 + threadIdx.x;
    if (i >= n4) return;
    float4 v = reinterpret_cast<const float4*>(in)[i];
    ushort4 h, L;
    h.x = f2bf(v.x); L.x = f2bf(v.x - bf2f(h.x));
    h.y = f2bf(v.y); L.y = f2bf(v.y - bf2f(h.y));
    h.z = f2bf(v.z); L.z = f2bf(v.z - bf2f(h.z));
    h.w = f2bf(v.w); L.w = f2bf(v.w - bf2f(h.w));
    reinterpret_cast<ushort4*>(hi)[i] = h;
    reinterpret_cast<ushort4*>(lo)[i] = L;
}

// ---- prep: split + transpose: in[K][N] fp32 -> hiT/loT[N][K] bf16 ---------
__global__ __launch_bounds__(256) void splitT_hl(
    const float* __restrict__ in, unsigned short* __restrict__ hiT,
    unsigned short* __restrict__ loT, int K, int N)
{
    __shared__ float t[32][33];
    const int n0 = blockIdx.x * 32, k0 = blockIdx.y * 32;
    const int tx = threadIdx.x & 31, ty = threadIdx.x >> 5;
    #pragma unroll
    for (int r = 0; r < 32; r += 8)
        t[ty + r][tx] = in[(size_t)(k0 + ty + r) * N + n0 + tx];
    __syncthreads();
    #pragma unroll
    for (int r = 0; r < 32; r += 8) {
        float v = t[tx][ty + r];
        unsigned short h = f2bf(v);
        size_t o = (size_t)(n0 + ty + r) * K + k0 + tx;
        hiT[o] = h;
        loT[o] = f2bf(v - bf2f(h));
    }
}

// ---- prep: V transpose (bf16 hi/lo): qkv V-section -> Vt[bh][d][seq] ------
__global__ __launch_bounds__(256) void vt_prep_bf(
    const unsigned short* __restrict__ qh, const unsigned short* __restrict__ ql,
    unsigned short* __restrict__ Vth, unsigned short* __restrict__ Vtl)
{
    __shared__ unsigned short th[32][34], tl[32][34];
    const int s0 = blockIdx.x * 32, d0 = blockIdx.y * 32, bh = blockIdx.z;
    const int b = bh >> 4, h = bh & 15;
    const int tx = threadIdx.x & 31, ty = threadIdx.x >> 5;
    #pragma unroll
    for (int r = 0; r < 32; r += 8) {
        size_t src = ((size_t)b * SEQ + s0 + ty + r) * 3072 + 2048 + h * 64 + d0 + tx;
        th[ty + r][tx] = qh[src];
        tl[ty + r][tx] = ql[src];
    }
    __syncthreads();
    #pragma unroll
    for (int r = 0; r < 32; r += 8) {
        size_t o = ((size_t)bh * 64 + d0 + ty + r) * SEQ + s0 + tx;
        Vth[o] = th[tx][ty + r];
        Vtl[o] = tl[tx][ty + r];
    }
}

// ---- split-bf16 3-pass MFMA GEMM core -------------------------------------
// MODE 0: C fp32 + bias.  MODE 1: C -> hi/lo bf16, cols<1024 scaled by
//         0.125*log2(e) (Q pre-scale so attention softmax can use exp2).
template <int MODE>
__global__ __launch_bounds__(256) void gemm_bt_3p_t(
    const unsigned short* __restrict__ Ah, const unsigned short* __restrict__ Al,
    const unsigned short* __restrict__ Bh, const unsigned short* __restrict__ Bl,
    const float* __restrict__ bias, float* __restrict__ C,
    unsigned short* __restrict__ Ch, unsigned short* __restrict__ Cl,
    int M, int N, int K)
{
    __shared__ __align__(16) unsigned short sAh[128 * 32];
    __shared__ __align__(16) unsigned short sAl[128 * 32];
    __shared__ __align__(16) unsigned short sBh[128 * 32];
    __shared__ __align__(16) unsigned short sBl[128 * 32];

    const int tid = threadIdx.x;
    const int l = tid & 63, w = tid >> 6;
    const int wr = w >> 1, wc = w & 1;
    const int bm = blockIdx.x * 128, bn = blockIdx.y * 128;

    const int srow = w * 32 + (l >> 2);
    const int scol = (l & 3) * 8;
    const size_t a0 = (size_t)(bm + srow) * K + scol;
    const size_t a1 = (size_t)(bm + srow + 16) * K + scol;
    const size_t b0 = (size_t)(bn + srow) * K + scol;
    const size_t b1 = (size_t)(bn + srow + 16) * K + scol;

    const int fr = l & 15;
    const int fk = (l >> 4) * 8;

    f32x4 acc[4][4];
    #pragma unroll
    for (int i = 0; i < 4; ++i)
        #pragma unroll
        for (int j = 0; j < 4; ++j)
            acc[i][j] = (f32x4){0.f, 0.f, 0.f, 0.f};

    for (int k0 = 0; k0 < K; k0 += 32) {
        __syncthreads();
        GLD(Ah + a0 + k0, sAh + w * 1024);
        GLD(Ah + a1 + k0, sAh + w * 1024 + 512);
        GLD(Al + a0 + k0, sAl + w * 1024);
        GLD(Al + a1 + k0, sAl + w * 1024 + 512);
        GLD(Bh + b0 + k0, sBh + w * 1024);
        GLD(Bh + b1 + k0, sBh + w * 1024 + 512);
        GLD(Bl + b0 + k0, sBl + w * 1024);
        GLD(Bl + b1 + k0, sBl + w * 1024 + 512);
        __syncthreads();

        short8 vah[4], val[4], vbh[4], vbl[4];
        #pragma unroll
        for (int i = 0; i < 4; ++i) {
            int ar = (wr * 64 + i * 16 + fr) * 32 + fk;
            int br = (wc * 64 + i * 16 + fr) * 32 + fk;
            vah[i] = *reinterpret_cast<const short8*>(&sAh[ar]);
            val[i] = *reinterpret_cast<const short8*>(&sAl[ar]);
            vbh[i] = *reinterpret_cast<const short8*>(&sBh[br]);
            vbl[i] = *reinterpret_cast<const short8*>(&sBl[br]);
        }
        __builtin_amdgcn_s_setprio(1);
        #pragma unroll
        for (int i = 0; i < 4; ++i)
            #pragma unroll
            for (int j = 0; j < 4; ++j) {
                acc[i][j] = __builtin_amdgcn_mfma_f32_16x16x32_bf16(vah[i], vbh[j], acc[i][j], 0, 0, 0);
                acc[i][j] = __builtin_amdgcn_mfma_f32_16x16x32_bf16(vah[i], vbl[j], acc[i][j], 0, 0, 0);
                acc[i][j] = __builtin_amdgcn_mfma_f32_16x16x32_bf16(val[i], vbh[j], acc[i][j], 0, 0, 0);
            }
        __builtin_amdgcn_s_setprio(0);
    }

    #pragma unroll
    for (int i = 0; i < 4; ++i) {
        #pragma unroll
        for (int j = 0; j < 4; ++j) {
            int row = bm + wr * 64 + i * 16 + (l >> 4) * 4;
            int col = bn + wc * 64 + j * 16 + fr;
            if (MODE == 0) {
                float bb = bias ? bias[col] : 0.f;
                #pragma unroll
                for (int r = 0; r < 4; ++r)
                    C[(size_t)(row + r) * N + col] = acc[i][j][r] + bb;
            } else {
                // Q section scaled by 1/8 * log2(e) so attn uses exp2 natively
                float sc = (col < 1024) ? 0.18033688011112042f : 1.0f;
                #pragma unroll
                for (int r = 0; r < 4; ++r) {
                    float v = acc[i][j][r] * sc;
                    unsigned short hh = f2bf(v);
                    size_t o = (size_t)(row + r) * N + col;
                    Ch[o] = hh;
                    Cl[o] = f2bf(v - bf2f(hh));
                }
            }
        }
    }
}

// ---- MFMA flash attention: 32x32 MFMA, swapped QK^T, in-register P --------
// QBLK=128 (32 q-rows/wave), KVBLK=64. No P LDS round-trip: P distributed
// to PV B-fragments via v_cvt_pk_bf16_f32 + v_permlane32_swap_b32 (T12).
// LDS: sK dbuf 32K + sV 16K = 48KB -> 3 blocks/CU.
__global__ __launch_bounds__(256) void flash_attn_mfma(
    const unsigned short* __restrict__ QKh, const unsigned short* __restrict__ QKl,
    const unsigned short* __restrict__ Vth, const unsigned short* __restrict__ Vtl,
    unsigned short* __restrict__ out_hi, unsigned short* __restrict__ out_lo)
{
    __shared__ __align__(16) unsigned short sK[2][2][64 * 64];  // [buf][hi/lo]
    __shared__ __align__(16) unsigned short sV[2][64 * 64];     // [hi/lo]

    const int qt = blockIdx.x, head = blockIdx.y, b = blockIdx.z;
    const int tid = threadIdx.x;
    const int l = tid & 63, w = tid >> 6;
    const int q5 = l & 31, hf = l >> 5;     // q col within 32; k-half

    const size_t kgbase = (size_t)b * SEQ * 3072 + 1024 + head * 64;
    const size_t vtb    = ((size_t)(b * NH + head)) * 64 * SEQ;

    int sg_r[2], sg_c[2];
    #pragma unroll
    for (int i2 = 0; i2 < 2; ++i2) {
        int gi = (w * 2 + i2) * 64 + l;
        sg_r[i2] = gi >> 3;
        sg_c[i2] = (gi & 7) ^ (sg_r[i2] & 7);    // inverse-swizzled source chunk
    }

    #define STAGE_K(cbuf, kt_) do {                                            \
        _Pragma("unroll")                                                      \
        for (int i2 = 0; i2 < 2; ++i2) {                                       \
            int i = w * 2 + i2;                                                \
            size_t gk = kgbase + (size_t)((kt_) * 64 + sg_r[i2]) * 3072 + sg_c[i2] * 8; \
            GLD(QKh + gk, (char*)&sK[cbuf][0][0] + i * 1024);                  \
            GLD(QKl + gk, (char*)&sK[cbuf][1][0] + i * 1024);                  \
        }                                                                      \
    } while (0)

    #define STAGE_V(kt_) do {                                                  \
        _Pragma("unroll")                                                      \
        for (int i2 = 0; i2 < 2; ++i2) {                                       \
            int i = w * 2 + i2;                                                \
            size_t gv = vtb + (size_t)sg_r[i2] * SEQ + (size_t)(kt_) * 64 + sg_c[i2] * 8; \
            GLD(Vth + gv, (char*)&sV[0][0] + i * 1024);                        \
            GLD(Vtl + gv, (char*)&sV[1][0] + i * 1024);                        \
        }                                                                      \
    } while (0)

    // ---- Q B-fragments to registers (pre-scaled by 0.125*log2e in GEMM1) --
    // B-frag for 32x32x16: col=q5, k-chunk = 16*s + 8*hf + {0..7}
    const int qrow = qt * 128 + w * 32 + q5;
    short8 qhr[4], qlr[4];
    {
        const size_t qb = ((size_t)b * SEQ + qrow) * 3072 + head * 64;
        #pragma unroll
        for (int s = 0; s < 4; ++s) {
            qhr[s] = *reinterpret_cast<const short8*>(QKh + qb + s * 16 + hf * 8);
            qlr[s] = *reinterpret_cast<const short8*>(QKl + qb + s * 16 + hf * 8);
        }
    }

    float m_ = -1e30f, l_ = 0.f;            // log2-domain running max / sum
    f32x16 oacc0, oacc1;                    // O^T: col=q5, d-tiles 0/1
    #pragma unroll
    for (int r = 0; r < 16; ++r) { oacc0[r] = 0.f; oacc1[r] = 0.f; }

    union FragU { unsigned u[4]; short8 s8; };

    STAGE_K(0, 0);
    int cur = 0;

    for (int kt = 0; kt < SEQ / 64; ++kt) {
        __syncthreads();                    // (A) K[cur] ready; sV free
        STAGE_V(kt);
        if (kt + 1 < SEQ / 64) STAGE_K(cur ^ 1, kt + 1);

        const char* kbh = (const char*)&sK[cur][0][0];
        const char* kbl = (const char*)&sK[cur][1][0];

        // ---- S^T = K Q^T, 32x32x16, 3-pass. sacc{0,1}: key-tiles 0/1 ------
        f32x16 sacc0, sacc1;
        #pragma unroll
        for (int r = 0; r < 16; ++r) { sacc0[r] = 0.f; sacc1[r] = 0.f; }
        #pragma unroll
        for (int s = 0; s < 4; ++s) {
            int cb = 32 * s + 16 * hf;
            short8 k0h = *reinterpret_cast<const short8*>(kbh + swz(q5, cb));
            short8 k0l = *reinterpret_cast<const short8*>(kbl + swz(q5, cb));
            short8 k1h = *reinterpret_cast<const short8*>(kbh + swz(32 + q5, cb));
            short8 k1l = *reinterpret_cast<const short8*>(kbl + swz(32 + q5, cb));
            __builtin_amdgcn_s_setprio(1);
            sacc0 = __builtin_amdgcn_mfma_f32_32x32x16_bf16(k0h, qhr[s], sacc0, 0, 0, 0);
            sacc0 = __builtin_amdgcn_mfma_f32_32x32x16_bf16(k0h, qlr[s], sacc0, 0, 0, 0);
            sacc0 = __builtin_amdgcn_mfma_f32_32x32x16_bf16(k0l, qhr[s], sacc0, 0, 0, 0);
            sacc1 = __builtin_amdgcn_mfma_f32_32x32x16_bf16(k1h, qhr[s], sacc1, 0, 0, 0);
            sacc1 = __builtin_amdgcn_mfma_f32_32x32x16_bf16(k1h, qlr[s], sacc1, 0, 0, 0);
            sacc1 = __builtin_amdgcn_mfma_f32_32x32x16_bf16(k1l, qhr[s], sacc1, 0, 0, 0);
            __builtin_amdgcn_s_setprio(0);
        }

        // ---- online softmax (base 2). Lane holds 32 scores for q=q5. ------
        float mloc = fmaxf(sacc0[0], sacc1[0]);
        #pragma unroll
        for (int r = 1; r < 16; ++r) mloc = fmaxf(mloc, fmaxf(sacc0[r], sacc1[r]));
        mloc = fmaxf(mloc, __shfl_xor(mloc, 32));
        float mnew  = fmaxf(m_, mloc);
        float alpha = exp2f(m_ - mnew);
        m_ = mnew;

        float ssum = 0.f;
        short8 pbh[4], pbl[4];   // PV B-frags: kslice = ktile*2 + {0,1}

        #pragma unroll
        for (int jt = 0; jt < 2; ++jt) {
            float pv[16];
            #pragma unroll
            for (int r = 0; r < 16; ++r) {
                float sv = (jt == 0) ? sacc0[r] : sacc1[r];
                pv[r] = exp2f(sv - mnew);
                ssum += pv[r];
            }
            // hi-plane packed dwords (pre-swap)
            unsigned A0, A1, B0, B1, C0, C1, D0, D1;
            asm("v_cvt_pk_bf16_f32 %0, %1, %2" : "=v"(A0) : "v"(pv[0]),  "v"(pv[1]));
            asm("v_cvt_pk_bf16_f32 %0, %1, %2" : "=v"(A1) : "v"(pv[2]),  "v"(pv[3]));
            asm("v_cvt_pk_bf16_f32 %0, %1, %2" : "=v"(B0) : "v"(pv[4]),  "v"(pv[5]));
            asm("v_cvt_pk_bf16_f32 %0, %1, %2" : "=v"(B1) : "v"(pv[6]),  "v"(pv[7]));
            asm("v_cvt_pk_bf16_f32 %0, %1, %2" : "=v"(C0) : "v"(pv[8]),  "v"(pv[9]));
            asm("v_cvt_pk_bf16_f32 %0, %1, %2" : "=v"(C1) : "v"(pv[10]), "v"(pv[11]));
            asm("v_cvt_pk_bf16_f32 %0, %1, %2" : "=v"(D0) : "v"(pv[12]), "v"(pv[13]));
            asm("v_cvt_pk_bf16_f32 %0, %1, %2" : "=v"(D1) : "v"(pv[14]), "v"(pv[15]));
            // residuals (exact: pv - bf2f(hi))
            float rv[16];
            rv[0]  = pv[0]  - __uint_as_float(A0 << 16);
            rv[1]  = pv[1]  - __uint_as_float(A0 & 0xffff0000u);
            rv[2]  = pv[2]  - __uint_as_float(A1 << 16);
            rv[3]  = pv[3]  - __uint_as_float(A1 & 0xffff0000u);
            rv[4]  = pv[4]  - __uint_as_float(B0 << 16);
            rv[5]  = pv[5]  - __uint_as_float(B0 & 0xffff0000u);
            rv[6]  = pv[6]  - __uint_as_float(B1 << 16);
            rv[7]  = pv[7]  - __uint_as_float(B1 & 0xffff0000u);
            rv[8]  = pv[8]  - __uint_as_float(C0 << 16);
            rv[9]  = pv[9]  - __uint_as_float(C0 & 0xffff0000u);
            rv[10] = pv[10] - __uint_as_float(C1 << 16);
            rv[11] = pv[11] - __uint_as_float(C1 & 0xffff0000u);
            rv[12] = pv[12] - __uint_as_float(D0 << 16);
            rv[13] = pv[13] - __uint_as_float(D0 & 0xffff0000u);
            rv[14] = pv[14] - __uint_as_float(D1 << 16);
            rv[15] = pv[15] - __uint_as_float(D1 & 0xffff0000u);
            unsigned E0, E1, F0, F1, G0, G1, H0, H1;
            asm("v_cvt_pk_bf16_f32 %0, %1, %2" : "=v"(E0) : "v"(rv[0]),  "v"(rv[1]));
            asm("v_cvt_pk_bf16_f32 %0, %1, %2" : "=v"(E1) : "v"(rv[2]),  "v"(rv[3]));
            asm("v_cvt_pk_bf16_f32 %0, %1, %2" : "=v"(F0) : "v"(rv[4]),  "v"(rv[5]));
            asm("v_cvt_pk_bf16_f32 %0, %1, %2" : "=v"(F1) : "v"(rv[6]),  "v"(rv[7]));
            asm("v_cvt_pk_bf16_f32 %0, %1, %2" : "=v"(G0) : "v"(rv[8]),  "v"(rv[9]));
            asm("v_cvt_pk_bf16_f32 %0, %1, %2" : "=v"(G1) : "v"(rv[10]), "v"(rv[11]));
            asm("v_cvt_pk_bf16_f32 %0, %1, %2" : "=v"(H0) : "v"(rv[12]), "v"(rv[13]));
            asm("v_cvt_pk_bf16_f32 %0, %1, %2" : "=v"(H1) : "v"(rv[14]), "v"(rv[15]));
            // half-exchange: (d0,d2) = swap(X0,Y0), (d1,d3) = swap(X1,Y1)
            asm("v_permlane32_swap_b32 %0, %1" : "+v"(A0), "+v"(B0));
            asm("v_permlane32_swap_b32 %0, %1" : "+v"(A1), "+v"(B1));
            asm("v_permlane32_swap_b32 %0, %1" : "+v"(C0), "+v"(D0));
            asm("v_permlane32_swap_b32 %0, %1" : "+v"(C1), "+v"(D1));
            asm("v_permlane32_swap_b32 %0, %1" : "+v"(E0), "+v"(F0));
            asm("v_permlane32_swap_b32 %0, %1" : "+v"(E1), "+v"(F1));
            asm("v_permlane32_swap_b32 %0, %1" : "+v"(G0), "+v"(H0));
            asm("v_permlane32_swap_b32 %0, %1" : "+v"(G1), "+v"(H1));
            FragU fh0; fh0.u[0] = A0; fh0.u[1] = A1; fh0.u[2] = B0; fh0.u[3] = B1;
            FragU fh1; fh1.u[0] = C0; fh1.u[1] = C1; fh1.u[2] = D0; fh1.u[3] = D1;
            FragU fl0; fl0.u[0] = E0; fl0.u[1] = E1; fl0.u[2] = F0; fl0.u[3] = F1;
            FragU fl1; fl1.u[0] = G0; fl1.u[1] = G1; fl1.u[2] = H0; fl1.u[3] = H1;
            pbh[jt * 2 + 0] = fh0.s8;
            pbh[jt * 2 + 1] = fh1.s8;
            pbl[jt * 2 + 0] = fl0.s8;
            pbl[jt * 2 + 1] = fl1.s8;
        }

        ssum += __shfl_xor(ssum, 32);
        l_ = l_ * alpha + ssum;
        #pragma unroll
        for (int r = 0; r < 16; ++r) { oacc0[r] *= alpha; oacc1[r] *= alpha; }

        __syncthreads();                    // (B) V(kt) arrived

        // ---- O^T += V^T P^T : A = V-frag (rows=d), B = P-frag -------------
        const char* vbh = (const char*)&sV[0][0];
        const char* vbl = (const char*)&sV[1][0];
        #pragma unroll
        for (int kpv = 0; kpv < 4; ++kpv) {
            int cb = 32 * kpv + 16 * hf;
            short8 v0h = *reinterpret_cast<const short8*>(vbh + swz(q5, cb));
            short8 v0l = *reinterpret_cast<const short8*>(vbl + swz(q5, cb));
            short8 v1h = *reinterpret_cast<const short8*>(vbh + swz(32 + q5, cb));
            short8 v1l = *reinterpret_cast<const short8*>(vbl + swz(32 + q5, cb));
            __builtin_amdgcn_s_setprio(1);
            oacc0 = __builtin_amdgcn_mfma_f32_32x32x16_bf16(v0h, pbh[kpv], oacc0, 0, 0, 0);
            oacc0 = __builtin_amdgcn_mfma_f32_32x32x16_bf16(v0l, pbh[kpv], oacc0, 0, 0, 0);
            oacc0 = __builtin_amdgcn_mfma_f32_32x32x16_bf16(v0h, pbl[kpv], oacc0, 0, 0, 0);
            oacc1 = __builtin_amdgcn_mfma_f32_32x32x16_bf16(v1h, pbh[kpv], oacc1, 0, 0, 0);
            oacc1 = __builtin_amdgcn_mfma_f32_32x32x16_bf16(v1l, pbh[kpv], oacc1, 0, 0, 0);
            oacc1 = __builtin_amdgcn_mfma_f32_32x32x16_bf16(v1h, pbl[kpv], oacc1, 0, 0, 0);
            __builtin_amdgcn_s_setprio(0);
        }
        cur ^= 1;
    }

    // ---- epilogue: O^T/l -> hi/lo bf16; d = (reg&3)+8*(reg>>2)+4*hf+32*dt --
    float linv = 1.f / l_;
    #pragma unroll
    for (int dt = 0; dt < 2; ++dt) {
        #pragma unroll
        for (int rq = 0; rq < 4; ++rq) {
            int dbase = dt * 32 + rq * 8 + 4 * hf;
            ushort4 h4, l4;
            #pragma unroll
            for (int c = 0; c < 4; ++c) {
                float v = ((dt == 0) ? oacc0[rq * 4 + c] : oacc1[rq * 4 + c]) * linv;
                unsigned short hh = f2bf(v);
                ((unsigned short*)&h4)[c] = hh;
                ((unsigned short*)&l4)[c] = f2bf(v - bf2f(hh));
            }
            size_t o = ((size_t)b * SEQ + qrow) * DM + head * 64 + dbase;
            *reinterpret_cast<ushort4*>(out_hi + o) = h4;
            *reinterpret_cast<ushort4*>(out_lo + o) = l4;
        }
    }
    #undef STAGE_K
    #undef STAGE_V
}

extern "C" void kernel_launch(void* const* d_in, const int* in_sizes, int n_in,
                              void* d_out, int out_size, void* d_ws, size_t ws_size,
                              hipStream_t stream) {
    const float* x     = (const float*)d_in[0];
    const float* w_qkv = (const float*)d_in[1];
    const float* w_out = (const float*)d_in[2];
    const float* b_out = (const float*)d_in[3];
    float* out = (float*)d_out;

    const int M = BATCH * SEQ;                    // 8192

    char* ws = (char*)d_ws;
    unsigned short* qkv_h = (unsigned short*)ws;                         ws += (size_t)M * 3072 * 2;
    unsigned short* qkv_l = (unsigned short*)ws;                         ws += (size_t)M * 3072 * 2;
    unsigned short* x_hi  = (unsigned short*)ws;                         ws += (size_t)M * DM * 2;
    unsigned short* x_lo  = (unsigned short*)ws;                         ws += (size_t)M * DM * 2;
    unsigned short* wqT_h = (unsigned short*)ws;                         ws += (size_t)3072 * DM * 2;
    unsigned short* wqT_l = (unsigned short*)ws;                         ws += (size_t)3072 * DM * 2;
    unsigned short* woT_h = (unsigned short*)ws;                         ws += (size_t)DM * DM * 2;
    unsigned short* woT_l = (unsigned short*)ws;                         ws += (size_t)DM * DM * 2;
    unsigned short* at_hi = (unsigned short*)ws;                         ws += (size_t)M * DM * 2;
    unsigned short* at_lo = (unsigned short*)ws;

    unsigned short* Vth = x_hi;   // alias: dead after GEMM1
    unsigned short* Vtl = x_lo;

    dim3 blk(256);

    split_hl<<<dim3((M * DM / 4 + 255) / 256), blk, 0, stream>>>(x, x_hi, x_lo, M * DM / 4);
    splitT_hl<<<dim3(3072 / 32, DM / 32), blk, 0, stream>>>(w_qkv, wqT_h, wqT_l, DM, 3 * DM);
    splitT_hl<<<dim3(DM / 32, DM / 32), blk, 0, stream>>>(w_out, woT_h, woT_l, DM, DM);

    gemm_bt_3p_t<1><<<dim3(M / 128, 3 * DM / 128), blk, 0, stream>>>(
        x_hi, x_lo, wqT_h, wqT_l, nullptr, nullptr, qkv_h, qkv_l, M, 3 * DM, DM);

    vt_prep_bf<<<dim3(SEQ / 32, DH / 32, BATCH * NH), blk, 0, stream>>>(
        qkv_h, qkv_l, Vth, Vtl);

    flash_attn_mfma<<<dim3(SEQ / 128, NH, BATCH), blk, 0, stream>>>(
        qkv_h, qkv_l, Vth, Vtl, at_hi, at_lo);

    gemm_bt_3p_t<0><<<dim3(M / 128, DM / 128), blk, 0, stream>>>(
        at_hi, at_lo, woT_h, woT_l, b_out, out, nullptr, nullptr, M, DM, DM);
}